// Round 12
// baseline (262.092 us; speedup 1.0000x reference)
//
#include <hip/hip_runtime.h>

// ---------------------------------------------------------------------------
// GCN 2-layer forward, CSR gather with per-edge dinv lookup:
//   h = X @ W1 (raw bf16);  h2 = drop(relu(dn*(Σ dinv[j] h_j + dn h_i) + b1))
//   g = h2 @ W2 (fused matvec, f32);  out[i] = dn*(Σ dinv[j] g_j + dn g_i) + b2
// CSR entries = src only (4B); pads -> node N with dinv[N]=0 (exact zero).
// GEMM1: B-frags direct from global (10KB LDS), split-bf16 (3 MFMA), fused
// with count_slot (mega1). Layer-2 GEMM fused into gather (per-node matvec,
// f32 h2 staged in LDS, W2 L1-resident).
// Dropout mask = JAX threefry2x32, key(42), partitionable fold (o0^o1), p=0.5.
//   (verified rounds 3-11)
// ---------------------------------------------------------------------------

typedef __attribute__((ext_vector_type(8))) short bf16x8;          // MFMA A/B
typedef __attribute__((ext_vector_type(4))) float f32x4;           // MFMA C/D
typedef __attribute__((ext_vector_type(8))) unsigned short us8;

__device__ __forceinline__ unsigned tf_rotl(unsigned x, int d) {
    return (x << d) | (x >> (32 - d));
}

__device__ __forceinline__ bool dropout_keep(unsigned flat_idx) {
    const unsigned K0 = 0u, K1 = 42u;
    const unsigned K2 = K0 ^ K1 ^ 0x1BD11BDAu;
    unsigned x0 = 0u, x1 = flat_idx;
    x0 += K0; x1 += K1;
#define TF_R(r) { x0 += x1; x1 = tf_rotl(x1, (r)); x1 ^= x0; }
    TF_R(13) TF_R(15) TF_R(26) TF_R(6)
    x0 += K1; x1 += K2 + 1u;
    TF_R(17) TF_R(29) TF_R(16) TF_R(24)
    x0 += K2; x1 += K0 + 2u;
    TF_R(13) TF_R(15) TF_R(26) TF_R(6)
    x0 += K0; x1 += K1 + 3u;
    TF_R(17) TF_R(29) TF_R(16) TF_R(24)
    x0 += K1; x1 += K2 + 4u;
    TF_R(13) TF_R(15) TF_R(26) TF_R(6)
    x0 += K2; x1 += K0 + 5u;
#undef TF_R
    return (((x0 ^ x1) >> 31) & 1u) == 0u;   // fold bits1^bits2, keep if < 2^31
}

// ---- bf16 helpers ----------------------------------------------------------
__device__ __forceinline__ unsigned short bf16_rn(float x) {
    unsigned u = __float_as_uint(x);
    unsigned r = u + 0x7FFFu + ((u >> 16) & 1u);
    return (unsigned short)(r >> 16);
}
__device__ __forceinline__ void split_bf16(float x, unsigned short& h, unsigned short& l) {
    h = bf16_rn(x);
    float fh = __uint_as_float(((unsigned)h) << 16);
    l = bf16_rn(x - fh);
}
__device__ __forceinline__ void split4(float4 v, ushort4& h, ushort4& l) {
    unsigned short h0, h1, h2, h3, l0, l1, l2, l3;
    split_bf16(v.x, h0, l0); split_bf16(v.y, h1, l1);
    split_bf16(v.z, h2, l2); split_bf16(v.w, h3, l3);
    h = make_ushort4(h0, h1, h2, h3);
    l = make_ushort4(l0, l1, l2, l3);
}

// int32 vs int64 edge-index autodetect (values < 50000 -> i64 hi words are 0).
__device__ __forceinline__ int ei_stride(const int* __restrict__ ei) {
    bool i64 = true;
#pragma unroll
    for (int k = 1; k <= 15; k += 2) i64 = i64 && (ei[k] == 0);
    return i64 ? 2 : 1;
}

// ---------------------------------------------------------------------------
// gemm core (layer 1): Yb = bf16( X @ W ), MFMA 16x16x32, BM=64, BK=32.
// B-fragments direct from global (L2-resident), reg double-buffered.
// ---------------------------------------------------------------------------
template <int K_, int NOUT_>
__device__ __forceinline__ void gemm_core(const float* __restrict__ Xf,
                                          const unsigned short* __restrict__ wT_hi,
                                          const unsigned short* __restrict__ wT_lo,
                                          unsigned short* __restrict__ Yb,
                                          int nrows, int bid) {
    constexpr int BM = 64, BK = 32, NKT = K_ / BK;
    constexpr int CT = NOUT_ / 64;            // col-tiles per wave
    constexpr int LDW = BK + 8;               // 80B row stride (16B multiple)

    __shared__ __attribute__((aligned(16))) unsigned short xs_hi[BM][LDW];
    __shared__ __attribute__((aligned(16))) unsigned short xs_lo[BM][LDW];

    const int t = threadIdx.x;
    const int wave = t >> 6, lane = t & 63;
    const int m16 = lane & 15, kg = lane >> 4;
    const int row0 = bid * BM;
    const int n0 = wave * (16 * CT);

    f32x4 acc[4][CT];
#pragma unroll
    for (int r = 0; r < 4; ++r)
#pragma unroll
        for (int c = 0; c < CT; ++c) acc[r][c] = {0.f, 0.f, 0.f, 0.f};

    float4 xpre[2];
    bf16x8 bh[2][CT], bl[2][CT];

#pragma unroll
    for (int i = 0; i < 2; ++i) {
        int idx = t + i * 256;
        int r = idx >> 3, c4 = idx & 7;
        int gr = row0 + r;
        xpre[i] = (gr < nrows) ? *(const float4*)&Xf[(size_t)gr * K_ + c4 * 4]
                               : make_float4(0.f, 0.f, 0.f, 0.f);
    }
#pragma unroll
    for (int c = 0; c < CT; ++c) {
        const size_t wrow = (size_t)(n0 + c * 16 + m16) * K_ + kg * 8;
        bh[0][c] = *(const bf16x8*)&wT_hi[wrow];
        bl[0][c] = *(const bf16x8*)&wT_lo[wrow];
    }

#pragma unroll
    for (int kb = 0; kb < NKT; ++kb) {
        const int cur = kb & 1, nxt = cur ^ 1;
#pragma unroll
        for (int i = 0; i < 2; ++i) {
            int idx = t + i * 256;
            int r = idx >> 3, c4 = idx & 7;
            ushort4 h, l;
            split4(xpre[i], h, l);
            *(ushort4*)&xs_hi[r][c4 * 4] = h;
            *(ushort4*)&xs_lo[r][c4 * 4] = l;
        }
        __syncthreads();

        if (kb + 1 < NKT) {
            const int koff = (kb + 1) * BK;
#pragma unroll
            for (int i = 0; i < 2; ++i) {
                int idx = t + i * 256;
                int r = idx >> 3, c4 = idx & 7;
                int gr = row0 + r;
                xpre[i] = (gr < nrows) ? *(const float4*)&Xf[(size_t)gr * K_ + koff + c4 * 4]
                                       : make_float4(0.f, 0.f, 0.f, 0.f);
            }
#pragma unroll
            for (int c = 0; c < CT; ++c) {
                const size_t wrow = (size_t)(n0 + c * 16 + m16) * K_ + koff + kg * 8;
                bh[nxt][c] = *(const bf16x8*)&wT_hi[wrow];
                bl[nxt][c] = *(const bf16x8*)&wT_lo[wrow];
            }
        }

#pragma unroll
        for (int r = 0; r < 4; ++r) {
            bf16x8 ah = *(const bf16x8*)&xs_hi[r * 16 + m16][kg * 8];
            bf16x8 al = *(const bf16x8*)&xs_lo[r * 16 + m16][kg * 8];
#pragma unroll
            for (int c = 0; c < CT; ++c) {
                acc[r][c] = __builtin_amdgcn_mfma_f32_16x16x32_bf16(ah, bh[cur][c], acc[r][c], 0, 0, 0);
                acc[r][c] = __builtin_amdgcn_mfma_f32_16x16x32_bf16(ah, bl[cur][c], acc[r][c], 0, 0, 0);
                acc[r][c] = __builtin_amdgcn_mfma_f32_16x16x32_bf16(al, bh[cur][c], acc[r][c], 0, 0, 0);
            }
        }
        __syncthreads();
    }

#pragma unroll
    for (int r = 0; r < 4; ++r) {
#pragma unroll
        for (int j = 0; j < 4; ++j) {
            int gr = row0 + r * 16 + kg * 4 + j;
            if (gr < nrows) {
#pragma unroll
                for (int c = 0; c < CT; ++c)
                    Yb[(size_t)gr * NOUT_ + n0 + c * 16 + m16] = bf16_rn(acc[r][c][j]);
            }
        }
    }
}

// ---------------------------------------------------------------------------
// K0: W1 split (blocks 0..127) ∥ deg zeroing (rest).
// ---------------------------------------------------------------------------
__global__ __launch_bounds__(256)
void prep(const float* __restrict__ W1,
          unsigned short* __restrict__ wT1_hi, unsigned short* __restrict__ wT1_lo,
          unsigned* __restrict__ deg, int N) {
    const int b = blockIdx.x, t = threadIdx.x;
    if (b < 128) {
        int idx = b * 256 + t;
        int k = idx / 128, n = idx % 128;
        unsigned short h, l;
        split_bf16(W1[idx], h, l);
        wT1_hi[(size_t)n * 256 + k] = h;
        wT1_lo[(size_t)n * 256 + k] = l;
    } else {
        int i = (b - 128) * 256 + t;
        if (i < N) deg[i] = 0;
    }
}

// ---------------------------------------------------------------------------
// K1: gemm1 (blocks 0..nGemm-1) ∥ count_slot (rest).
// ---------------------------------------------------------------------------
__global__ __launch_bounds__(256)
void mega1(const float* __restrict__ x, const unsigned short* __restrict__ wT1_hi,
           const unsigned short* __restrict__ wT1_lo, unsigned short* __restrict__ buffA,
           const int* __restrict__ ei, unsigned* __restrict__ deg,
           unsigned* __restrict__ aux, int N, int E, int nGemm) {
    if ((int)blockIdx.x < nGemm) {
        gemm_core<256, 128>(x, wT1_hi, wT1_lo, buffA, N, blockIdx.x);
        return;
    }
    int e = (blockIdx.x - nGemm) * 256 + threadIdx.x;
    if (e >= E) return;
    size_t st = ei_stride(ei);
    aux[e] = atomicAdd(&deg[ei[((size_t)E + e) * st]], 1u);
}

// ---------------------------------------------------------------------------
// scan phase1: per-block padded-deg sums + dinv (dinv[N]=0 for pads).
// ---------------------------------------------------------------------------
__global__ __launch_bounds__(256)
void scan_phase1(const unsigned* __restrict__ deg, unsigned* __restrict__ blockSums,
                 float* __restrict__ dinv, int N) {
    const int i = blockIdx.x * 256 + threadIdx.x;
    const int lane = threadIdx.x & 63, wave = threadIdx.x >> 6;
    if (blockIdx.x == 0 && threadIdx.x == 0) dinv[N] = 0.0f;   // zero-node weight
    unsigned v = 0;
    if (i < N) {
        unsigned d = deg[i];
        v = (d + 7u) & ~7u;
        dinv[i] = rsqrtf((float)(d + 1u));   // +1 = self loop
    }
    unsigned s = v;
#pragma unroll
    for (int o = 32; o > 0; o >>= 1) s += __shfl_down(s, o, 64);
    __shared__ unsigned ws[4];
    if (lane == 0) ws[wave] = s;
    __syncthreads();
    if (threadIdx.x == 0)
        blockSums[blockIdx.x] = ws[0] + ws[1] + ws[2] + ws[3];
}

// phase3b: inline scan of block sums + local scan -> rowptr; pads -> node N.
__global__ __launch_bounds__(256)
void scan_phase3b(const unsigned* __restrict__ deg, const unsigned* __restrict__ blockSums,
                  unsigned* __restrict__ rowptr, int* __restrict__ csr, int N, int nb) {
    __shared__ unsigned s[256];
    const int t = threadIdx.x;

    unsigned bsv = (t < nb) ? blockSums[t] : 0u;
    s[t] = bsv;
    __syncthreads();
    for (int off = 1; off < 256; off <<= 1) {
        unsigned u = (t >= off) ? s[t - off] : 0u;
        __syncthreads();
        s[t] += u;
        __syncthreads();
    }
    const unsigned off0 = (blockIdx.x == 0) ? 0u : s[blockIdx.x - 1];
    __syncthreads();

    const int i = blockIdx.x * 256 + t;
    unsigned d = 0, v = 0;
    if (i < N) { d = deg[i]; v = (d + 7u) & ~7u; }
    s[t] = v;
    __syncthreads();
    for (int off = 1; off < 256; off <<= 1) {
        unsigned u = (t >= off) ? s[t - off] : 0u;
        __syncthreads();
        s[t] += u;
        __syncthreads();
    }
    const unsigned incl = s[t];
    if (i < N) {
        const unsigned rp = off0 + incl - v;
        rowptr[i] = rp;
        if (i == N - 1) rowptr[N] = off0 + incl;
        for (unsigned u = d; u < v; ++u) csr[rp + u] = N;   // pad -> zero-weight node
    }
}

// atomic-free placement: csr[slot] = src (4B)
__global__ void place_edges(const int* __restrict__ ei, const unsigned* __restrict__ rowptr,
                            const unsigned* __restrict__ aux, int* __restrict__ csr, int E) {
    int e = blockIdx.x * blockDim.x + threadIdx.x;
    if (e >= E) return;
    size_t st = ei_stride(ei);
    int s = ei[(size_t)e * st];
    int d = ei[((size_t)E + e) * st];
    csr[rowptr[d] + aux[e]] = s;
}

// ---------------------------------------------------------------------------
// Fused layer-1 aggregate + relu + dropout + (h2 @ W2) matvec.
// One wave per node. h2 kept f32; staged in LDS; W2 read [k][n] (L1-resident).
// gout[node][lane] = bf16( Σ_k h2[k] * W2[k*64+lane] )
// ---------------------------------------------------------------------------
__global__ __launch_bounds__(256)
void gather_fused(const unsigned* __restrict__ hs /*bf16x2*/, const int* __restrict__ csr,
                  const unsigned* __restrict__ rowptr, const float* __restrict__ dinv,
                  const float* __restrict__ bias, const float* __restrict__ W2,
                  unsigned short* __restrict__ gout, int N) {
    __shared__ float h2s[4][128];
    const int wv = threadIdx.x >> 6;
    const int node = blockIdx.x * 4 + wv;
    if (node >= N) return;
    const int lane = threadIdx.x & 63;
    const unsigned beg = rowptr[node];
    const unsigned end = rowptr[node + 1];   // multiple of 8; pads -> node N (dinv 0)
    const float dn = dinv[node];

    unsigned v = hs[(size_t)node * 64 + lane];
    float ax = dn * __uint_as_float(v << 16);
    float ay = dn * __uint_as_float(v & 0xffff0000u);
    for (unsigned k = beg; k < end; k += 8) {
        int j[8];
#pragma unroll
        for (int u = 0; u < 8; ++u) j[u] = csr[k + u];
        unsigned w8[8];
        float dv[8];
#pragma unroll
        for (int u = 0; u < 8; ++u) { w8[u] = hs[(size_t)j[u] * 64 + lane]; dv[u] = dinv[j[u]]; }
#pragma unroll
        for (int u = 0; u < 8; ++u) {
            ax = fmaf(dv[u], __uint_as_float(w8[u] << 16), ax);
            ay = fmaf(dv[u], __uint_as_float(w8[u] & 0xffff0000u), ay);
        }
    }
    const int f0 = 2 * lane;
    float o0 = fmaxf(fmaf(dn, ax, bias[f0]), 0.0f);
    float o1 = fmaxf(fmaf(dn, ay, bias[f0 + 1]), 0.0f);
    unsigned base = (unsigned)node * 128u + (unsigned)f0;
    o0 = dropout_keep(base) ? 2.0f * o0 : 0.0f;
    o1 = dropout_keep(base + 1u) ? 2.0f * o1 : 0.0f;

    // stage h2 row (f32) in LDS; only this wave reads it back (no barrier).
    ((float2*)h2s[wv])[lane] = make_float2(o0, o1);

    // matvec: g[lane] = sum_k h2[k] * W2[k*64+lane]  (W2 L1-resident, coalesced)
    float g = 0.0f;
    const float4* h4p = (const float4*)h2s[wv];
#pragma unroll 4
    for (int k4 = 0; k4 < 32; ++k4) {
        float4 h4 = h4p[k4];
        const float* wp = &W2[(size_t)(k4 * 4) * 64 + lane];
        g = fmaf(h4.x, wp[0], g);
        g = fmaf(h4.y, wp[64], g);
        g = fmaf(h4.z, wp[128], g);
        g = fmaf(h4.w, wp[192], g);
    }
    gout[(size_t)node * 64 + lane] = bf16_rn(g);
}

// ---------------------------------------------------------------------------
// Gather layer 2 (F=64, bf16 in, f32 out). 8-deep batches.
// ---------------------------------------------------------------------------
__global__ __launch_bounds__(256)
void gather_out(const unsigned short* __restrict__ hs /*bf16*/, const int* __restrict__ csr,
                const unsigned* __restrict__ rowptr, const float* __restrict__ dinv,
                const float* __restrict__ bias, float* __restrict__ outp, int N) {
    const int node = blockIdx.x * 4 + (threadIdx.x >> 6);
    if (node >= N) return;
    const int lane = threadIdx.x & 63;
    const unsigned beg = rowptr[node];
    const unsigned end = rowptr[node + 1];
    const float dn = dinv[node];

    float acc = dn * __uint_as_float(((unsigned)hs[(size_t)node * 64 + lane]) << 16);
    for (unsigned k = beg; k < end; k += 8) {
        int j[8];
#pragma unroll
        for (int u = 0; u < 8; ++u) j[u] = csr[k + u];
        unsigned short w8[8];
        float dv[8];
#pragma unroll
        for (int u = 0; u < 8; ++u) { w8[u] = hs[(size_t)j[u] * 64 + lane]; dv[u] = dinv[j[u]]; }
#pragma unroll
        for (int u = 0; u < 8; ++u)
            acc = fmaf(dv[u], __uint_as_float(((unsigned)w8[u]) << 16), acc);
    }
    outp[(size_t)node * 64 + lane] = fmaf(dn, acc, bias[lane]);
}

extern "C" void kernel_launch(void* const* d_in, const int* in_sizes, int n_in,
                              void* d_out, int out_size, void* d_ws, size_t ws_size,
                              hipStream_t stream) {
    const float* x  = (const float*)d_in[0];
    const int*   ei = (const int*)d_in[1];
    const float* W1 = (const float*)d_in[2];
    const float* b1 = (const float*)d_in[3];
    const float* W2 = (const float*)d_in[4];
    const float* b2 = (const float*)d_in[5];
    float* out = (float*)d_out;

    const int Fdim = 256, Hdim = 128, Cdim = 64;
    const int N = in_sizes[0] / Fdim;   // 50000
    const int E = in_sizes[1] / 2;      // 800000
    const int CSR_CAP = E + 7 * N;      // padded-slot upper bound
    const int NB = (N + 255) / 256;     // scan blocks (196, <=256 required)

    // workspace: wT1_hi|lo | buffA[(N+1)*128] bf16 (h) | buffG[(N+1)*64] bf16 (g) |
    //   deg[N] | dinv[N+1] | rowptr[N+1] | blockSums[NB] | aux[E] | csr[CSR_CAP]
    unsigned short* wT1_hi = (unsigned short*)d_ws;
    unsigned short* wT1_lo = wT1_hi + 256 * 128;
    unsigned short* buffA  = wT1_lo + 256 * 128;
    unsigned short* buffG  = buffA + (size_t)(N + 1) * Hdim;
    unsigned* deg    = (unsigned*)(buffG + (size_t)(N + 1) * Cdim);
    float*    dinv   = (float*)(deg + N);
    unsigned* rowptr = (unsigned*)(dinv + (N + 1));
    unsigned* blockSums = rowptr + (N + 1);
    unsigned* aux    = blockSums + NB;
    int*      csr    = (int*)(aux + E);

    const int nGemm1 = (N + 63) / 64;
    const int nCount = (E + 255) / 256;

    // K0: W1 split ∥ deg zeroing
    prep<<<128 + NB, 256, 0, stream>>>(W1, wT1_hi, wT1_lo, deg, N);
    // K1: gemm1 (raw bf16 h) ∥ count_slot
    mega1<<<nGemm1 + nCount, 256, 0, stream>>>(x, wT1_hi, wT1_lo, buffA, ei, deg, aux, N, E, nGemm1);
    // CSR finish
    scan_phase1<<<NB, 256, 0, stream>>>(deg, blockSums, dinv, N);
    scan_phase3b<<<NB, 256, 0, stream>>>(deg, blockSums, rowptr, csr, N, NB);
    place_edges<<<nCount, 256, 0, stream>>>(ei, rowptr, aux, csr, E);

    // fused: layer-1 aggregate + relu + dropout + h2@W2 -> g (bf16)
    gather_fused<<<(N + 3) / 4, 256, 0, stream>>>((const unsigned*)buffA, csr, rowptr, dinv, b1,
                                                  W2, buffG, N);
    // layer-2 aggregate -> out
    gather_out<<<(N + 3) / 4, 256, 0, stream>>>(buffG, csr, rowptr, dinv, b2, out, N);
}